// Round 8
// baseline (255.799 us; speedup 1.0000x reference)
//
#include <hip/hip_runtime.h>
#include <hip/hip_fp16.h>
#include <math.h>

#define CAP 64          // max incidences per node (mean deg = 8)
#define D1 128
#define D2 16
#define C_OUT 40
#define K_EDGE 32
#define CLAMP_LO 1e-7f
#define CLAMP_HI 10.0f
#define SQRT_INV31 0.1796053020267749f   // sqrt(1/31)

typedef unsigned short ushort_t;
typedef _Float16 hv2 __attribute__((ext_vector_type(2)));

__device__ __forceinline__ hv2 hv2_zero() {
    hv2 z; z.x = (_Float16)0; z.y = (_Float16)0; return z;
}

// Fused setup: clip+square -> Hp (fp16), incidence-list build (uint16 edge
// ids), W1 transpose, zero rows of S/S2.
__global__ __launch_bounds__(256) void k_setup(const float* __restrict__ x,
                                               hv2* __restrict__ Hp,
                                               const int* __restrict__ idx,
                                               int* __restrict__ deg,
                                               ushort_t* __restrict__ lst,
                                               const float* __restrict__ W1,
                                               float* __restrict__ W1t,
                                               hv2* __restrict__ S,
                                               float* __restrict__ S2,
                                               int n4, int total, int E) {
    int i = blockIdx.x * 256 + threadIdx.x;
    if (i < n4) {                                  // clip + square, 4 floats
        float4 v = ((const float4*)x)[i];
        v.x = fminf(fmaxf(v.x, CLAMP_LO), CLAMP_HI);
        v.y = fminf(fmaxf(v.y, CLAMP_LO), CLAMP_HI);
        v.z = fminf(fmaxf(v.z, CLAMP_LO), CLAMP_HI);
        v.w = fminf(fmaxf(v.w, CLAMP_LO), CLAMP_HI);
        hv2 h0; h0.x = (_Float16)(v.x * v.x); h0.y = (_Float16)(v.y * v.y);
        hv2 h1; h1.x = (_Float16)(v.z * v.z); h1.y = (_Float16)(v.w * v.w);
        Hp[2 * i] = h0; Hp[2 * i + 1] = h1;
    }
    if (i < total) {                               // incidence build
        int n = idx[i];
        int e = i >> 5;                            // k = 32
        int pos = atomicAdd(&deg[n], 1);
        if (pos < CAP) lst[n * CAP + pos] = (ushort_t)e;
    }
    if (i < D1 * D2) W1t[(i & 15) * D1 + (i >> 4)] = W1[i];
    if (i < 64) S[(size_t)E * 64 + i] = hv2_zero();
    if (i < D2) S2[(size_t)E * D2 + i] = 0.0f;
}

// S[e,:] = sum of Hp[node,:] over the edge's 32 nodes. FOUR edges per wave;
// two coalesced 64-id loads; packed-fp16 accumulation (2 groups of 16 per
// edge for rounding control); 16 edges per 256-block.
__global__ __launch_bounds__(256) void k_edge_sum(const hv2* __restrict__ Hp,
                                                  const int* __restrict__ idx,
                                                  hv2* __restrict__ S, int E) {
    int w = threadIdx.x >> 6;
    int lane = threadIdx.x & 63;
    int eA = (blockIdx.x * 4 + w) * 4;
    if (eA + 4 > E) eA = E - 4;                  // overlap duplicates, benign
    int nid0 = idx[eA * K_EDGE + lane];          // ids of edges eA, eA+1
    int nid1 = idx[eA * K_EDGE + 64 + lane];     // ids of edges eA+2, eA+3
    hv2 acc[4][2];
#pragma unroll
    for (int k = 0; k < 4; k++) { acc[k][0] = hv2_zero(); acc[k][1] = hv2_zero(); }
#pragma unroll
    for (int j = 0; j < K_EDGE; j++) {
        int g = j >> 4;                          // accumulation group
        int nA = __builtin_amdgcn_readlane(nid0, j);
        int nB = __builtin_amdgcn_readlane(nid0, 32 + j);
        int nC = __builtin_amdgcn_readlane(nid1, j);
        int nD = __builtin_amdgcn_readlane(nid1, 32 + j);
        acc[0][g] += Hp[(size_t)nA * 64 + lane];
        acc[1][g] += Hp[(size_t)nB * 64 + lane];
        acc[2][g] += Hp[(size_t)nC * 64 + lane];
        acc[3][g] += Hp[(size_t)nD * 64 + lane];
    }
#pragma unroll
    for (int k = 0; k < 4; k++)
        S[(size_t)(eA + k) * 64 + lane] = acc[k][0] + acc[k][1];
}

// Fused layer-1 node kernel. TWO nodes per wave; uint16 lst slots 0..15
// (lanes 0-15: node0, 16-31: node1). Zero-row padding: unused slots carry
// edge id E (row E of S zeroed) so sqrt(max(0-hp,0)) == 0. Packed fp16 math.
__global__ __launch_bounds__(256) void k_node1(const hv2* __restrict__ Hp,
                                               const hv2* __restrict__ S,
                                               const int* __restrict__ deg,
                                               const ushort_t* __restrict__ lst,
                                               const float* __restrict__ W1t,
                                               const float* __restrict__ b1,
                                               _Float16* __restrict__ Hp2, int N, int E) {
    int w = threadIdx.x >> 6;
    int lane = threadIdx.x & 63;
    int pair = blockIdx.x * 4 + w;              // wave handles nodes 2p, 2p+1
    int n0 = pair * 2, n1 = n0 + 1;             // N even
    int c = lane & 15, j = lane >> 4;

    int2 dg2 = ((const int2*)deg)[pair];
    int dg0 = min(dg2.x, CAP), dg1 = min(dg2.y, CAP);
    int sl = lane & 15;
    int nodesel = (lane < 16) ? n0 : n1;
    ushort_t idu = (lane < 32) ? lst[nodesel * CAP + sl] : (ushort_t)0;
    int dsel = (lane < 16) ? dg0 : dg1;
    int e_sel = (lane < 32 && sl < dsel) ? (int)idu : E;

    hv2 hph0 = Hp[(size_t)n0 * 64 + lane];
    hv2 hph1 = Hp[(size_t)n1 * 64 + lane];

    // two bursts of 16 independent gathers
    hv2 sv0[16], sv1[16];
#pragma unroll
    for (int t = 0; t < 16; t++) {
        int e = __builtin_amdgcn_readlane(e_sel, t);
        sv0[t] = S[(size_t)e * 64 + lane];
    }
#pragma unroll
    for (int t = 0; t < 16; t++) {
        int e = __builtin_amdgcn_readlane(e_sel, 16 + t);
        sv1[t] = S[(size_t)e * 64 + lane];
    }

    hv2 z = hv2_zero();
    hv2 A0a = z, A0b = z, A1a = z, A1b = z;
#pragma unroll
    for (int t = 0; t < 16; t += 2) {
        hv2 d0 = __builtin_elementwise_max(sv0[t] - hph0, z);
        hv2 d1 = __builtin_elementwise_max(sv0[t + 1] - hph0, z);
        A0a += __builtin_elementwise_sqrt(d0);
        A0b += __builtin_elementwise_sqrt(d1);
    }
#pragma unroll
    for (int t = 0; t < 16; t += 2) {
        hv2 d0 = __builtin_elementwise_max(sv1[t] - hph1, z);
        hv2 d1 = __builtin_elementwise_max(sv1[t + 1] - hph1, z);
        A1a += __builtin_elementwise_sqrt(d0);
        A1b += __builtin_elementwise_sqrt(d1);
    }
    for (int t = 16; t < dg0; t++) {            // rare tails (P ~ 0.4%)
        int e = lst[n0 * CAP + t];
        hv2 d = __builtin_elementwise_max(S[(size_t)e * 64 + lane] - hph0, z);
        A0a += __builtin_elementwise_sqrt(d);
    }
    for (int t = 16; t < dg1; t++) {
        int e = lst[n1 * CAP + t];
        hv2 d = __builtin_elementwise_max(S[(size_t)e * 64 + lane] - hph1, z);
        A1a += __builtin_elementwise_sqrt(d);
    }
    hv2 A0 = A0a + A0b, A1 = A1a + A1b;

    float ns00 = __builtin_amdgcn_sqrtf((float)hph0.x) + (float)A0.x * SQRT_INV31;
    float ns01 = __builtin_amdgcn_sqrtf((float)hph0.y) + (float)A0.y * SQRT_INV31;
    float ns10 = __builtin_amdgcn_sqrtf((float)hph1.x) + (float)A1.x * SQRT_INV31;
    float ns11 = __builtin_amdgcn_sqrtf((float)hph1.y) + (float)A1.y * SQRT_INV31;

    __shared__ float AHs[4][2][D1];             // wave-private
    AHs[w][0][2 * lane]     = ns00;
    AHs[w][0][2 * lane + 1] = ns01;
    AHs[w][1][2 * lane]     = ns10;
    AHs[w][1][2 * lane + 1] = ns11;

    float v0 = ns00 + ns01, v1 = ns10 + ns11;
#pragma unroll
    for (int m = 1; m < 64; m <<= 1) {
        v0 += __shfl_xor(v0, m, 64);
        v1 += __shfl_xor(v1, m, 64);
    }
    float r0 = __builtin_amdgcn_rcpf(v0);
    float r1 = __builtin_amdgcn_rcpf(v1);

    __threadfence_block();                      // LDS visibility within wave

    // ns[128] @ W1[128,16] for both nodes, sharing the W1t fragment.
    const float4* a0p = (const float4*)(&AHs[w][0][j * 32]);
    const float4* a1p = (const float4*)(&AHs[w][1][j * 32]);
    const float4* w1p = (const float4*)(W1t + c * D1 + j * 32);
    float p0 = 0.0f, p1 = 0.0f;
#pragma unroll
    for (int tt = 0; tt < 8; tt++) {
        float4 wv = w1p[tt];
        float4 x0 = a0p[tt];
        float4 x1 = a1p[tt];
        p0 += x0.x * wv.x + x0.y * wv.y + x0.z * wv.z + x0.w * wv.w;
        p1 += x1.x * wv.x + x1.y * wv.y + x1.z * wv.z + x1.w * wv.w;
    }
    p0 += __shfl_xor(p0, 16, 64);
    p0 += __shfl_xor(p0, 32, 64);
    p1 += __shfl_xor(p1, 16, 64);
    p1 += __shfl_xor(p1, 32, 64);
    if (lane < D2) {
        float bb = b1[c];
        float o0 = bb + p0 * r0;
        float o1 = bb + p1 * r1;
        float cl0 = fminf(fmaxf(o0, CLAMP_LO), CLAMP_HI);   // relu + next clip
        float cl1 = fminf(fmaxf(o1, CLAMP_LO), CLAMP_HI);
        Hp2[(size_t)n0 * D2 + c] = (_Float16)(cl0 * cl0);
        Hp2[(size_t)n1 * D2 + c] = (_Float16)(cl1 * cl1);
    }
}

// S2[e,:] = sum over 32 nodes of Hp2[node,:] (fp16 in, fp32 out). 8 lanes
// per edge (2 cols packed per lane), 8 edges per wave, 32 per block.
__global__ __launch_bounds__(256) void k_edge_sum2(const hv2* __restrict__ Hp2v,
                                                   const int* __restrict__ idx,
                                                   float2* __restrict__ S2v, int E) {
    int w = threadIdx.x >> 6;
    int lane = threadIdx.x & 63;
    int sub = lane >> 3;
    int cp = lane & 7;
    int e = (blockIdx.x * 4 + w) * 8 + sub;
    if (e >= E) e = E - 1;                       // duplicate, benign
    const int* ip = idx + (size_t)e * K_EDGE;
    hv2 g0 = hv2_zero(), g1 = hv2_zero();
#pragma unroll
    for (int j = 0; j < 16; j++)  g0 += Hp2v[(size_t)ip[j] * 8 + cp];
#pragma unroll
    for (int j = 16; j < 32; j++) g1 += Hp2v[(size_t)ip[j] * 8 + cp];
    float2 s; s.x = (float)g0.x + (float)g1.x; s.y = (float)g0.y + (float)g1.y;
    S2v[(size_t)e * 8 + cp] = s;
}

// Fused layer-2 node kernel. TWO nodes per wave: node = lane bit 5, two
// 16-lane subgroups per node split the 16 gather slots. uint16 lst.
__global__ __launch_bounds__(256) void k_node2(const _Float16* __restrict__ Hp2,
                                               const float* __restrict__ S2,
                                               const int* __restrict__ deg,
                                               const ushort_t* __restrict__ lst,
                                               const float* __restrict__ W2,
                                               const float* __restrict__ b2,
                                               float* __restrict__ out, int N, int E) {
    int w = threadIdx.x >> 6;
    int lane = threadIdx.x & 63;
    int pair = blockIdx.x * 4 + w;
    int n0 = pair * 2, n1 = n0 + 1;
    int col = lane & 15;
    int node = lane >> 5;                       // 0 or 1
    int gg = (lane >> 4) & 1;                   // subgroup within node
    int nn = node ? n1 : n0;

    int2 dg2 = ((const int2*)deg)[pair];
    int dg0 = min(dg2.x, CAP), dg1 = min(dg2.y, CAP);
    int sl = lane & 15;
    ushort_t idu = (lane < 32) ? lst[((lane < 16) ? n0 : n1) * CAP + sl] : (ushort_t)0;
    int dsel = (lane < 16) ? dg0 : dg1;
    int e_sel = (lane < 32 && sl < dsel) ? (int)idu : E;   // E = zero row of S2

    float hp = (float)Hp2[(size_t)nn * D2 + col];
    int dgn = node ? dg1 : dg0;

    // 8 slots per lane: {2t+gg}, t=0..7, from this node's 16 slots
    int ev[8];
#pragma unroll
    for (int t = 0; t < 8; t++) ev[t] = __shfl(e_sel, node * 16 + 2 * t + gg, 64);
    float sv[8];
#pragma unroll
    for (int t = 0; t < 8; t++) sv[t] = S2[(size_t)ev[t] * D2 + col];

    float acc = 0.0f;
#pragma unroll
    for (int t = 0; t < 8; t++)
        acc += __builtin_amdgcn_sqrtf(fmaxf(sv[t] - hp, 0.0f));
    for (int t = 16; t < dgn; t++) {            // rare tail; add once (gg==0)
        int e = lst[nn * CAP + t];
        float s = S2[(size_t)e * D2 + col];
        if (gg == 0) acc += __builtin_amdgcn_sqrtf(fmaxf(s - hp, 0.0f));
    }
    acc += __shfl_xor(acc, 16, 64);             // combine the node's 2 subgroups
    float ns = __builtin_amdgcn_sqrtf(hp) + acc * SQRT_INV31;

    float v = ns;
#pragma unroll
    for (int m = 1; m < 16; m <<= 1) v += __shfl_xor(v, m, 64);  // rowsum (16 cols)
    float r = __builtin_amdgcn_rcpf(v);

    __shared__ float AHs[4][2][D2];             // wave-private
    if (gg == 0) AHs[w][node][col] = ns * r;
    __threadfence_block();

    if (lane < C_OUT) {
        float o0 = b2[lane], o1 = o0;
#pragma unroll
        for (int i = 0; i < D2; i++) {
            float wv = W2[i * C_OUT + lane];
            o0 += AHs[w][0][i] * wv;
            o1 += AHs[w][1][i] * wv;
        }
        out[(size_t)n0 * C_OUT + lane] = o0;
        out[(size_t)n1 * C_OUT + lane] = o1;
    }
}

extern "C" void kernel_launch(void* const* d_in, const int* in_sizes, int n_in,
                              void* d_out, int out_size, void* d_ws, size_t ws_size,
                              hipStream_t stream) {
    const float* x   = (const float*)d_in[0];
    const int*   idx = (const int*)d_in[1];
    const float* W1  = (const float*)d_in[2];
    const float* b1  = (const float*)d_in[3];
    const float* W2  = (const float*)d_in[4];
    const float* b2  = (const float*)d_in[5];
    float* out = (float*)d_out;

    int N = in_sizes[0] / D1;     // 100000
    int E = in_sizes[1] / K_EDGE; // 25000

    // workspace layout (S and S2 have one extra zero row at index E)
    hv2* Hp = (hv2*)d_ws;                                   // N*64
    hv2* S  = Hp + (size_t)N * 64;                          // (E+1)*64
    _Float16* Hp2h = (_Float16*)(S + (size_t)(E + 1) * 64); // N*16
    float* S2   = (float*)(Hp2h + (size_t)N * D2);          // (E+1)*16
    float* W1t  = S2 + (size_t)(E + 1) * D2;                // 16*128
    int*   deg  = (int*)(W1t + D1 * D2);                    // N ints
    ushort_t* lst = (ushort_t*)(deg + N);                   // N*CAP uint16

    int total = E * K_EDGE;        // 800000
    int n4 = N * D1 / 4;           // 3200000

    (void)hipMemsetAsync(deg, 0, (size_t)N * sizeof(int), stream);
    k_setup<<<(n4 + 255) / 256, 256, 0, stream>>>(x, Hp, idx, deg, lst, W1, W1t,
                                                  S, S2, n4, total, E);
    k_edge_sum<<<(E + 15) / 16, 256, 0, stream>>>(Hp, idx, S, E);
    k_node1<<<N / 8, 256, 0, stream>>>(Hp, S, deg, lst, W1t, b1, Hp2h, N, E);
    k_edge_sum2<<<(E + 31) / 32, 256, 0, stream>>>((const hv2*)Hp2h, idx, (float2*)S2, E);
    k_node2<<<N / 8, 256, 0, stream>>>(Hp2h, S2, deg, lst, W2, b2, out, N, E);
}